// Round 5
// baseline (248.025 us; speedup 1.0000x reference)
//
#include <hip/hip_runtime.h>

typedef short bf16x8 __attribute__((ext_vector_type(8)));
typedef short short4v __attribute__((ext_vector_type(4)));
typedef float f32x4 __attribute__((ext_vector_type(4)));

__device__ __forceinline__ ushort f2b(float f) {
  union { float f; unsigned u; } v; v.f = f;
  unsigned r = v.u + 0x7FFF + ((v.u >> 16) & 1);
  return (ushort)(r >> 16);
}
__device__ __forceinline__ float b2f(ushort u) {
  union { unsigned u; float f; } v; v.u = ((unsigned)u) << 16;
  return v.f;
}
__device__ __forceinline__ unsigned cvtpk(float lo, float hi) {
  unsigned r;
  asm volatile("v_cvt_pk_bf16_f32 %0, %1, %2" : "=v"(r) : "v"(lo), "v"(hi));
  return r;
}
__device__ __forceinline__ f32x4 mfma16(bf16x8 a, bf16x8 b, f32x4 c) {
  return __builtin_amdgcn_mfma_f32_16x16x32_bf16(a, b, c, 0, 0, 0);
}

#define GLD_LDS16(g, l) \
  __builtin_amdgcn_global_load_lds((const __attribute__((address_space(1))) void*)(g), \
                                   (__attribute__((address_space(3))) void*)(l), 16, 0, 0)

// ---------------- cast fp32 -> bf16 (vectorized) ----------------
__global__ __launch_bounds__(256) void cast_bf16(const float* __restrict__ in,
                                                 ushort* __restrict__ out, int n4) {
  int i = blockIdx.x * 256 + threadIdx.x;
  if (i >= n4) return;
  float4 f = ((const float4*)in)[i];
  ushort4 u;
  u.x = f2b(f.x); u.y = f2b(f.y); u.z = f2b(f.z); u.w = f2b(f.w);
  ((ushort4*)out)[i] = u;
}

// ---------------- RoPE tables ----------------
__global__ void rope_tables_k(float* __restrict__ cosT, float* __restrict__ sinT) {
  int s = blockIdx.x, i = threadIdx.x;  // 64 threads
  float inv = powf(10000.0f, -(float)i * (1.0f / 64.0f));
  float f = (float)s * inv;
  cosT[s * 64 + i] = cosf(f);
  sinT[s * 64 + i] = sinf(f);
}

// LDS layout for both GEMMs: fragment-major. A K-tile [R rows][64 cols] bf16 is
// stored as (R/16)*2 fragments of 512 ushorts: frag = (row/16)*2 + (col/32),
// inside lane-major: us = frag*512 + lane*8, lane=(row%16) + (col%32/8)*16.
// Wave ds_read_b128 of one fragment = contiguous 1KB -> conflict-free by
// construction. Staging source coords absorb the permutation (LDS stays linear).

// ---------------- GEMM 256x256: C[M][N] = A[M][K]*B[N][K]^T ----------------
// 8 waves (2M x 4N), per-wave 128x64, BK=64. LDS 128KB: A 2x32KB | B 2x32KB.
// Counted vmcnt(8); 2 barriers/K-tile; never drains vmcnt in loop (T3+T4).
template <bool BF16OUT>
__global__ __launch_bounds__(512) void gemm256x256(const ushort* __restrict__ A,
                                                   const ushort* __restrict__ B,
                                                   void* __restrict__ Cout,
                                                   int M, int N, int K) {
  __shared__ __align__(16) ushort lds[65536];  // A: 2*16384 @0 ; B: 2*16384 @32768
  const int t = threadIdx.x;
  const int lane = t & 63, w = t >> 6;
  const int wr = w & 1, wc = w >> 1;
  const int l15 = lane & 15, l4 = lane >> 4;
  const int nbn = N >> 8;
  const long m0 = (long)(blockIdx.x / nbn) * 256;
  const long n0 = (long)(blockIdx.x % nbn) * 256;
  const int nk = K >> 6;

  // staging source coords (fragment-major inverse map)
  const int sr = ((t >> 7) << 4) + (t & 15);          // + r*64 per pass
  const int sc = ((t >> 6) & 1) * 32 + ((t >> 4) & 3) * 8;

#define STAGE_A2(kk, slot)                                                     \
  do {                                                                         \
    _Pragma("unroll") for (int r = 0; r < 4; ++r)                              \
        GLD_LDS16(A + (m0 + r * 64 + sr) * K + (kk) + sc,                      \
                  &lds[(slot) * 16384 + r * 4096 + t * 8]);                    \
  } while (0)
#define STAGE_B2(kk, slot)                                                     \
  do {                                                                         \
    _Pragma("unroll") for (int r = 0; r < 4; ++r)                              \
        GLD_LDS16(B + (n0 + r * 64 + sr) * K + (kk) + sc,                      \
                  &lds[32768 + (slot) * 16384 + r * 4096 + t * 8]);            \
  } while (0)

  f32x4 acc[8][4] = {};

  STAGE_A2(0, 0);
  STAGE_B2(0, 0);

  for (int j = 0; j < nk; ++j) {
    {
      int kn = j + 1; if (kn > nk - 1) kn = nk - 1;
      STAGE_A2(kn * 64, (j + 1) & 1);
      STAGE_B2(kn * 64, (j + 1) & 1);
    }
    asm volatile("s_waitcnt vmcnt(8)" ::: "memory");  // own tile-j loads done
    __builtin_amdgcn_s_barrier();                     // => all waves' tile-j done
    const int sa = j & 1;
    bf16x8 bfrag[4][2];
#pragma unroll
    for (int n = 0; n < 4; ++n)
#pragma unroll
      for (int ks = 0; ks < 2; ++ks)
        bfrag[n][ks] = *(const bf16x8*)(&lds[32768 + sa * 16384 +
                                             ((wc * 4 + n) * 2 + ks) * 512 + lane * 8]);
#pragma unroll
    for (int mp = 0; mp < 4; ++mp) {
      bf16x8 afrag[2][2];
#pragma unroll
      for (int i = 0; i < 2; ++i)
#pragma unroll
        for (int ks = 0; ks < 2; ++ks)
          afrag[i][ks] = *(const bf16x8*)(&lds[sa * 16384 +
                                               ((wr * 8 + mp * 2 + i) * 2 + ks) * 512 +
                                               lane * 8]);
      __builtin_amdgcn_s_setprio(1);
#pragma unroll
      for (int i = 0; i < 2; ++i)
#pragma unroll
        for (int n = 0; n < 4; ++n)
#pragma unroll
          for (int ks = 0; ks < 2; ++ks)
            acc[mp * 2 + i][n] = mfma16(afrag[i][ks], bfrag[n][ks], acc[mp * 2 + i][n]);
      __builtin_amdgcn_s_setprio(0);
    }
    __builtin_amdgcn_s_barrier();  // all waves done reading slot sa
  }
  asm volatile("s_waitcnt vmcnt(0)" ::: "memory");

#pragma unroll
  for (int m = 0; m < 8; ++m) {
#pragma unroll
    for (int n = 0; n < 4; ++n) {
      long mrow = m0 + wr * 128 + m * 16 + l4 * 4;
      long ncol = n0 + wc * 64 + n * 16 + l15;
#pragma unroll
      for (int r = 0; r < 4; ++r) {
        if constexpr (BF16OUT)
          ((ushort*)Cout)[(mrow + r) * N + ncol] = f2b(acc[m][n][r]);
        else
          ((float*)Cout)[(mrow + r) * N + ncol] = acc[m][n][r];
      }
    }
  }
#undef STAGE_A2
#undef STAGE_B2
}

// ---------------- GEMM 256x128 (out-proj: grid 256 = 1/CU) ----------------
// 8 waves (4M x 2N), per-wave 64x64. LDS 96KB: A 2x32KB | B 2x16KB. vmcnt(6).
template <bool BF16OUT>
__global__ __launch_bounds__(512) void gemm256(const ushort* __restrict__ A,
                                               const ushort* __restrict__ B,
                                               void* __restrict__ Cout,
                                               int M, int N, int K) {
  __shared__ __align__(16) ushort lds[49152];  // A: 2*16384 @0 ; B: 2*8192 @32768
  const int t = threadIdx.x;
  const int lane = t & 63, w = t >> 6;
  const int wr = w & 3, wc = w >> 2;
  const int l15 = lane & 15, l4 = lane >> 4;
  const int nbn = N >> 7;
  const long m0 = (long)(blockIdx.x / nbn) * 256;
  const long n0 = (long)(blockIdx.x % nbn) * 128;
  const int nk = K >> 6;

  const int sr = ((t >> 7) << 4) + (t & 15);
  const int sc = ((t >> 6) & 1) * 32 + ((t >> 4) & 3) * 8;

#define STAGE_A1(kk, slot)                                                     \
  do {                                                                         \
    _Pragma("unroll") for (int r = 0; r < 4; ++r)                              \
        GLD_LDS16(A + (m0 + r * 64 + sr) * K + (kk) + sc,                      \
                  &lds[(slot) * 16384 + r * 4096 + t * 8]);                    \
  } while (0)
#define STAGE_B1(kk, slot)                                                     \
  do {                                                                         \
    _Pragma("unroll") for (int r = 0; r < 2; ++r)                              \
        GLD_LDS16(B + (n0 + r * 64 + sr) * K + (kk) + sc,                      \
                  &lds[32768 + (slot) * 8192 + r * 4096 + t * 8]);             \
  } while (0)

  f32x4 acc[4][4] = {};

  STAGE_A1(0, 0);
  STAGE_B1(0, 0);

  for (int j = 0; j < nk; ++j) {
    {
      int kn = j + 1; if (kn > nk - 1) kn = nk - 1;
      STAGE_A1(kn * 64, (j + 1) & 1);
      STAGE_B1(kn * 64, (j + 1) & 1);
    }
    asm volatile("s_waitcnt vmcnt(6)" ::: "memory");
    __builtin_amdgcn_s_barrier();
    const int sa = j & 1;
    bf16x8 bfrag[4][2];
#pragma unroll
    for (int n = 0; n < 4; ++n)
#pragma unroll
      for (int ks = 0; ks < 2; ++ks)
        bfrag[n][ks] = *(const bf16x8*)(&lds[32768 + sa * 8192 +
                                             ((wc * 4 + n) * 2 + ks) * 512 + lane * 8]);
#pragma unroll
    for (int mp = 0; mp < 2; ++mp) {
      bf16x8 afrag[2][2];
#pragma unroll
      for (int i = 0; i < 2; ++i)
#pragma unroll
        for (int ks = 0; ks < 2; ++ks)
          afrag[i][ks] = *(const bf16x8*)(&lds[sa * 16384 +
                                               ((wr * 4 + mp * 2 + i) * 2 + ks) * 512 +
                                               lane * 8]);
      __builtin_amdgcn_s_setprio(1);
#pragma unroll
      for (int i = 0; i < 2; ++i)
#pragma unroll
        for (int n = 0; n < 4; ++n)
#pragma unroll
          for (int ks = 0; ks < 2; ++ks)
            acc[mp * 2 + i][n] = mfma16(afrag[i][ks], bfrag[n][ks], acc[mp * 2 + i][n]);
      __builtin_amdgcn_s_setprio(0);
    }
    __builtin_amdgcn_s_barrier();
  }
  asm volatile("s_waitcnt vmcnt(0)" ::: "memory");

#pragma unroll
  for (int m = 0; m < 4; ++m) {
#pragma unroll
    for (int n = 0; n < 4; ++n) {
      long mrow = m0 + wr * 64 + m * 16 + l4 * 4;
      long ncol = n0 + wc * 64 + n * 16 + l15;
#pragma unroll
      for (int r = 0; r < 4; ++r) {
        if constexpr (BF16OUT)
          ((ushort*)Cout)[(mrow + r) * N + ncol] = f2b(acc[m][n][r]);
        else
          ((float*)Cout)[(mrow + r) * N + ncol] = acc[m][n][r];
      }
    }
  }
#undef STAGE_A1
#undef STAGE_B1
}

// ---------------- RMSnorm + RoPE + layout (q,k) / cast+transpose (v) ----------------
__global__ __launch_bounds__(256) void postproc_k(const ushort* __restrict__ qkvb,
                                                  const float* __restrict__ cosT,
                                                  const float* __restrict__ sinT,
                                                  ushort* __restrict__ qb,
                                                  ushort* __restrict__ kb,
                                                  ushort* __restrict__ vtb) {
  const int lane = threadIdx.x & 63;
  const int s = blockIdx.x * 4 + (threadIdx.x >> 6);
  const int h = blockIdx.y;
  const int colbase = (h < 16) ? h * 128 : (h < 20 ? 2048 + (h - 16) * 128
                                                   : 2560 + (h - 20) * 128);
  const ushort* row = qkvb + (long)s * 3072 + colbase;
  float x1 = b2f(row[lane]), x2 = b2f(row[lane + 64]);
  if (h >= 20) {  // V: cast + transpose to [kvh][128][S]
    int kvh = h - 20;
    vtb[(long)(kvh * 128 + lane) * 4096 + s]      = f2b(x1);
    vtb[(long)(kvh * 128 + lane + 64) * 4096 + s] = f2b(x2);
    return;
  }
  float ss = x1 * x1 + x2 * x2;
#pragma unroll
  for (int m = 1; m < 64; m <<= 1) ss += __shfl_xor(ss, m);
  float rn = rsqrtf(ss * (1.0f / 128.0f) + 1.1920929e-07f);
  float c = cosT[s * 64 + lane], sn = sinT[s * 64 + lane];
  float x1n = x1 * rn, x2n = x2 * rn;
  float o1 = x1n * c + x2n * sn;
  float o2 = x2n * c - x1n * sn;
  if (h < 16) {
    const float scq = 0.08838834764831845f;  // 1/sqrt(128) folded into q
    ushort* dst = qb + ((long)h * 4096 + s) * 128;
    dst[lane] = f2b(o1 * scq);
    dst[lane + 64] = f2b(o2 * scq);
  } else {
    ushort* dst = kb + ((long)(h - 16) * 4096 + s) * 128;
    dst[lane] = f2b(o1);
    dst[lane + 64] = f2b(o2);
  }
}

// ---------------- flash attention: LDS-staged K/V, dbuf, KVBLK=64 ----------------
__global__ __launch_bounds__(512) void attn_k(const ushort* __restrict__ qb,
                                              const ushort* __restrict__ kb,
                                              const ushort* __restrict__ vtb,
                                              ushort* __restrict__ yb) {
  __shared__ __align__(16) ushort lds[32768];  // 64KB: buf{0,1} x (K 8192us | V 8192us)
  const int t = threadIdx.x;
  const int lane = t & 63, w = t >> 6;
  const int l15 = lane & 15, l4 = lane >> 4;
  const int q0 = ((int)gridDim.x - 1 - (int)blockIdx.x) * 128;  // heavy blocks first
  const int h = blockIdx.y, kvh = h >> 2;
  const int qw = q0 + w * 16;
  const int q = qw + l15;
  const int swz = l15 & 7;

  const ushort* Qp = qb + ((long)h * 4096 + q) * 128 + l4 * 8;
  bf16x8 qf[4];
#pragma unroll
  for (int c = 0; c < 4; ++c) qf[c] = *(const bf16x8*)(Qp + c * 32);

  const ushort* Kg = kb + (long)kvh * 4096 * 128;
  const ushort* Vg = vtb + (long)kvh * 128 * 4096;

  int kb_lo = q0 - 1023; if (kb_lo < 0) kb_lo = 0; kb_lo &= ~63;
  const int nt = (q0 + 127 - kb_lo) / 64 + 1;

  const int lbuA = (0 * 8 + w) * 512 + lane * 8;
  const int lbuB = (1 * 8 + w) * 512 + lane * 8;
  const int krA = lbuA >> 7, kcA = ((lbuA >> 3) & 15) ^ (krA & 7);
  const int krB = lbuB >> 7, kcB = ((lbuB >> 3) & 15) ^ (krB & 7);
  const int vrA = lbuA >> 6, vcA = ((lbuA >> 3) & 7) ^ (vrA & 7);
  const int vrB = lbuB >> 6, vcB = ((lbuB >> 3) & 7) ^ (vrB & 7);

#define STAGE(kbs, b)                                                        \
  do {                                                                       \
    ushort* Kl_ = &lds[(b) * 16384];                                         \
    ushort* Vl_ = &lds[(b) * 16384 + 8192];                                  \
    GLD_LDS16(Kg + (long)((kbs) + krA) * 128 + kcA * 8, Kl_ + lbuA);         \
    GLD_LDS16(Kg + (long)((kbs) + krB) * 128 + kcB * 8, Kl_ + lbuB);         \
    GLD_LDS16(Vg + (long)vrA * 4096 + (kbs) + vcA * 8, Vl_ + lbuA);          \
    GLD_LDS16(Vg + (long)vrB * 4096 + (kbs) + vcB * 8, Vl_ + lbuB);          \
  } while (0)

  f32x4 o[8] = {};
  float mrun = -1e30f, lrun = 0.0f;

  STAGE(kb_lo, 0);
  asm volatile("s_waitcnt vmcnt(0)" ::: "memory");
  __syncthreads();

  for (int ti = 0; ti < nt; ++ti) {
    const int kbs = kb_lo + ti * 64;
    const int cur = ti & 1;
    if (ti + 1 < nt) STAGE(kbs + 64, cur ^ 1);

    if (kbs + 63 >= qw - 1023 && kbs <= qw + 15) {
      const ushort* Kl = &lds[cur * 16384];
      const ushort* Vl = &lds[cur * 16384 + 8192];

      f32x4 sc[4];
#pragma unroll
      for (int st = 0; st < 4; ++st) {
        sc[st] = f32x4{0.f, 0.f, 0.f, 0.f};
        const ushort* kr = Kl + (st * 16 + l15) * 128;
#pragma unroll
        for (int c = 0; c < 4; ++c)
          sc[st] = mfma16(*(const bf16x8*)(kr + (((c * 4 + l4) ^ swz) * 8)), qf[c], sc[st]);
      }

      // wave-uniform fast path: interior tiles need no mask
      const bool full = (kbs + 64 <= qw) && (kbs >= qw - 1008);
      float s[16];
      if (full) {
#pragma unroll
        for (int st = 0; st < 4; ++st)
#pragma unroll
          for (int r = 0; r < 4; ++r) s[st * 4 + r] = sc[st][r];
      } else {
#pragma unroll
        for (int st = 0; st < 4; ++st)
#pragma unroll
          for (int r = 0; r < 4; ++r) {
            const int ki = kbs + st * 16 + l4 * 4 + r;
            s[st * 4 + r] = (ki <= q && ki > q - 1024) ? sc[st][r] : -1e30f;
          }
      }

      float m0a = fmaxf(fmaxf(s[0], s[1]), fmaxf(s[2], s[3]));
      float m1a = fmaxf(fmaxf(s[4], s[5]), fmaxf(s[6], s[7]));
      float m2a = fmaxf(fmaxf(s[8], s[9]), fmaxf(s[10], s[11]));
      float m3a = fmaxf(fmaxf(s[12], s[13]), fmaxf(s[14], s[15]));
      float mx = fmaxf(fmaxf(m0a, m1a), fmaxf(m2a, m3a));
      mx = fmaxf(mx, __shfl_xor(mx, 16));
      mx = fmaxf(mx, __shfl_xor(mx, 32));

      float mn;
      if (__all(mx <= mrun + 8.0f)) {  // T13 defer-max
        mn = mrun;
      } else {
        mn = fmaxf(mrun, mx);
        const float corr = __expf(mrun - mn);
        mrun = mn;
#pragma unroll
        for (int db = 0; db < 8; ++db)
#pragma unroll
          for (int r = 0; r < 4; ++r) o[db][r] *= corr;
        lrun *= corr;
      }

      float p[16];
#pragma unroll
      for (int j = 0; j < 16; ++j) p[j] = __expf(s[j] - mn);
      float ps = ((p[0] + p[1]) + (p[2] + p[3])) + ((p[4] + p[5]) + (p[6] + p[7]));
      ps += ((p[8] + p[9]) + (p[10] + p[11])) + ((p[12] + p[13]) + (p[14] + p[15]));
      ps += __shfl_xor(ps, 16);
      ps += __shfl_xor(ps, 32);
      lrun += ps;

      union { unsigned u[4]; bf16x8 v; } pa, pb;
      pa.u[0] = cvtpk(p[0], p[1]);   pa.u[1] = cvtpk(p[2], p[3]);
      pa.u[2] = cvtpk(p[4], p[5]);   pa.u[3] = cvtpk(p[6], p[7]);
      pb.u[0] = cvtpk(p[8], p[9]);   pb.u[1] = cvtpk(p[10], p[11]);
      pb.u[2] = cvtpk(p[12], p[13]); pb.u[3] = cvtpk(p[14], p[15]);

      const int co = 4 * (l4 & 1);
      const int c0 = (l4 >> 1) ^ swz, c1 = (2 + (l4 >> 1)) ^ swz;
      const int c2 = (4 + (l4 >> 1)) ^ swz, c3 = (6 + (l4 >> 1)) ^ swz;
#pragma unroll
      for (int db = 0; db < 8; ++db) {
        const ushort* vr = Vl + (db * 16 + l15) * 64;
        short4v a0 = *(const short4v*)(vr + c0 * 8 + co);
        short4v a1 = *(const short4v*)(vr + c1 * 8 + co);
        bf16x8 va = __builtin_shufflevector(a0, a1, 0, 1, 2, 3, 4, 5, 6, 7);
        o[db] = mfma16(va, pa.v, o[db]);
        short4v b0 = *(const short4v*)(vr + c2 * 8 + co);
        short4v b1 = *(const short4v*)(vr + c3 * 8 + co);
        bf16x8 vb = __builtin_shufflevector(b0, b1, 0, 1, 2, 3, 4, 5, 6, 7);
        o[db] = mfma16(vb, pb.v, o[db]);
      }
    }
    __syncthreads();
  }

  const float inv = 1.0f / lrun;
#pragma unroll
  for (int db = 0; db < 8; ++db)
#pragma unroll
    for (int r = 0; r < 4; ++r)
      yb[(long)q * 2048 + h * 128 + db * 16 + l4 * 4 + r] = f2b(o[db][r] * inv);
}

extern "C" void kernel_launch(void* const* d_in, const int* in_sizes, int n_in,
                              void* d_out, int out_size, void* d_ws, size_t ws_size,
                              hipStream_t stream) {
  (void)in_sizes; (void)n_in; (void)out_size; (void)ws_size;
  const float* x  = (const float*)d_in[0];
  const float* Wq = (const float*)d_in[1];
  const float* Wk = (const float*)d_in[2];
  const float* Wv = (const float*)d_in[3];
  const float* Wo = (const float*)d_in[4];
  const long S = 4096;
  ushort* ws   = (ushort*)d_ws;
  ushort* xb   = ws;                        // 4096*2048
  ushort* wqkv = xb + S * 2048;             // 3072*2048
  ushort* wob  = wqkv + 3072L * 2048;       // 2048*2048
  ushort* qkvb = wob + 2048L * 2048;        // 4096*3072
  ushort* qb   = qkvb + S * 3072;           // 16*4096*128
  ushort* kbuf = qb + S * 2048;             // 4*4096*128
  ushort* vtb  = kbuf + 4L * 4096 * 128;    // 4*128*4096
  ushort* yb   = vtb + 4L * 128 * 4096;     // 4096*2048
  float* cosT  = (float*)(yb + S * 2048);   // 4096*64
  float* sinT  = cosT + S * 64;             // 4096*64

  cast_bf16<<<dim3(8192), 256, 0, stream>>>(x, xb, (int)(S * 2048 / 4));
  cast_bf16<<<dim3(4096), 256, 0, stream>>>(Wq, wqkv, 2048 * 2048 / 4);
  cast_bf16<<<dim3(1024), 256, 0, stream>>>(Wk, wqkv + 2048L * 2048, 512 * 2048 / 4);
  cast_bf16<<<dim3(1024), 256, 0, stream>>>(Wv, wqkv + 2560L * 2048, 512 * 2048 / 4);
  cast_bf16<<<dim3(4096), 256, 0, stream>>>(Wo, wob, 2048 * 2048 / 4);

  gemm256x256<true><<<dim3(16 * 12), 512, 0, stream>>>(xb, wqkv, qkvb, 4096, 3072, 2048);
  rope_tables_k<<<dim3(4096), 64, 0, stream>>>(cosT, sinT);
  postproc_k<<<dim3(1024, 24), 256, 0, stream>>>(qkvb, cosT, sinT, qb, kbuf, vtb);
  attn_k<<<dim3(32, 16), 512, 0, stream>>>(qb, kbuf, vtb, yb);
  gemm256<false><<<dim3(16 * 16), 512, 0, stream>>>(yb, wob, d_out, 4096, 2048, 2048);
}

// Round 6
// 225.108 us; speedup vs baseline: 1.1018x; 1.1018x over previous
//
#include <hip/hip_runtime.h>

typedef short bf16x8 __attribute__((ext_vector_type(8)));
typedef float f32x4 __attribute__((ext_vector_type(4)));

__device__ __forceinline__ ushort f2b(float f) {
  union { float f; unsigned u; } v; v.f = f;
  unsigned r = v.u + 0x7FFF + ((v.u >> 16) & 1);
  return (ushort)(r >> 16);
}
__device__ __forceinline__ float b2f(ushort u) {
  union { unsigned u; float f; } v; v.u = ((unsigned)u) << 16;
  return v.f;
}
__device__ __forceinline__ unsigned cvtpk(float lo, float hi) {
  unsigned r;
  asm volatile("v_cvt_pk_bf16_f32 %0, %1, %2" : "=v"(r) : "v"(lo), "v"(hi));
  return r;
}
__device__ __forceinline__ f32x4 mfma16(bf16x8 a, bf16x8 b, f32x4 c) {
  return __builtin_amdgcn_mfma_f32_16x16x32_bf16(a, b, c, 0, 0, 0);
}

#define GLD_LDS16(g, l) \
  __builtin_amdgcn_global_load_lds((const __attribute__((address_space(1))) void*)(g), \
                                   (__attribute__((address_space(3))) void*)(l), 16, 0, 0)

// ---------------- cast fp32 -> bf16 (vectorized) ----------------
__global__ __launch_bounds__(256) void cast_bf16(const float* __restrict__ in,
                                                 ushort* __restrict__ out, int n4) {
  int i = blockIdx.x * 256 + threadIdx.x;
  if (i >= n4) return;
  float4 f = ((const float4*)in)[i];
  ushort4 u;
  u.x = f2b(f.x); u.y = f2b(f.y); u.z = f2b(f.z); u.w = f2b(f.w);
  ((ushort4*)out)[i] = u;
}

// ---------------- RoPE tables ----------------
__global__ void rope_tables_k(float* __restrict__ cosT, float* __restrict__ sinT) {
  int s = blockIdx.x, i = threadIdx.x;  // 64 threads
  float inv = powf(10000.0f, -(float)i * (1.0f / 64.0f));
  float f = (float)s * inv;
  cosT[s * 64 + i] = cosf(f);
  sinT[s * 64 + i] = sinf(f);
}

// =================== 8-phase pipelined GEMM (T2+T3+T4+T5) ===================
// C[M][N] = A[M][K]*B[N][K]^T. BK=64, 512 thr, 8 waves (2M x 4N).
// LDS: per matrix 4 half-regions [slot(2) x ks(2)], fragment-major
// (frag = 16 rows x 32 cols, lane-major: us = frag*512 + (l4*16+l15)*8) ->
// every wave ds_read_b128 is a contiguous 1KB: conflict-free by construction.
// Per 2-K-tile iter: 8 phases of {ds-read subtile | stage 1 half-tile |
// [vmcnt(VM) @ph4,8] | barrier | lgkmcnt(0) | setprio(1) MFMA setprio(0) |
// barrier}. vmcnt VM = LA+2*LB = 3 half-tiles in flight; never drains to 0.
// Region-overwrite safety: each half restaged >=2 phases after its last read.
template <int BM, int BN, bool BF16OUT>
__global__ __launch_bounds__(512, 2) void gemm8p(const ushort* __restrict__ A,
                                                 const ushort* __restrict__ B,
                                                 void* __restrict__ Cout,
                                                 int M, int N, int K) {
  constexpr int AF = BM / 64;       // A frags per phase (per wave)
  constexpr int BF = BN / 64;       // B frags per wave
  constexpr int MFR = BM / 32;      // acc M-frags per wave
  constexpr int LA = BM / 128;      // gld_lds per thread per A half
  constexpr int LB = BN / 128;
  constexpr int ASZ = BM * 32;      // ushorts per A half-region
  constexpr int BSZ = BN * 32;
  __shared__ __align__(16) ushort lds[4 * (ASZ + BSZ)];
  const int t = threadIdx.x;
  const int lane = t & 63, w = t >> 6;
  const int wr = w & 1, wc = w >> 1;
  const int l15 = lane & 15, l4 = lane >> 4;
  const int nbn = N / BN;
  const int nwg = (int)gridDim.x;
  int bid = (int)blockIdx.x;
  bid = (bid & 7) * (nwg >> 3) + (bid >> 3);  // XCD swizzle (nwg % 8 == 0)
  const long m0 = (long)(bid / nbn) * BM;
  const long n0 = (long)(bid % nbn) * BN;
  const int nk = K >> 6;
  const int rdl = (l4 * 16 + l15) * 8;

  f32x4 acc[MFR][BF] = {};
  bf16x8 af[AF], bf[BF];

#define STA(tile, ks)                                                          \
  do {                                                                         \
    const int tt_ = (tile) < nk ? (tile) : nk - 1;                             \
    _Pragma("unroll") for (int c = 0; c < LA; ++c) {                           \
      const int us_ = t * 8 + c * 4096;                                        \
      const int row_ = (us_ >> 9) * 16 + ((us_ >> 3) & 15);                    \
      const int col_ = ((us_ >> 7) & 3) * 8;                                   \
      GLD_LDS16(A + (m0 + row_) * K + tt_ * 64 + (ks) * 32 + col_,             \
                &lds[(((tile) & 1) * 2 + (ks)) * ASZ + us_]);                  \
    }                                                                          \
  } while (0)
#define STB(tile, ks)                                                          \
  do {                                                                         \
    const int tt_ = (tile) < nk ? (tile) : nk - 1;                             \
    _Pragma("unroll") for (int c = 0; c < LB; ++c) {                           \
      const int us_ = t * 8 + c * 4096;                                        \
      const int row_ = (us_ >> 9) * 16 + ((us_ >> 3) & 15);                    \
      const int col_ = ((us_ >> 7) & 3) * 8;                                   \
      GLD_LDS16(B + (n0 + row_) * K + tt_ * 64 + (ks) * 32 + col_,             \
                &lds[4 * ASZ + (((tile) & 1) * 2 + (ks)) * BSZ + us_]);        \
    }                                                                          \
  } while (0)
#define LDA8(slot, ks, mq)                                                     \
  _Pragma("unroll") for (int a = 0; a < AF; ++a)                               \
      af[a] = *(const bf16x8*)(&lds[((slot) * 2 + (ks)) * ASZ +                \
                                    (wr * MFR + (mq) * AF + a) * 512 + rdl]);
#define LDB8(slot, ks)                                                         \
  _Pragma("unroll") for (int b = 0; b < BF; ++b)                               \
      bf[b] = *(const bf16x8*)(&lds[4 * ASZ + ((slot) * 2 + (ks)) * BSZ +      \
                                    (wc * BF + b) * 512 + rdl]);
#define VMW()                                                                  \
  do {                                                                         \
    if constexpr (LA + 2 * LB == 6)                                            \
      asm volatile("s_waitcnt vmcnt(6)" ::: "memory");                         \
    else                                                                       \
      asm volatile("s_waitcnt vmcnt(5)" ::: "memory");                         \
  } while (0)
#define BARMM(mq)                                                              \
  do {                                                                         \
    __builtin_amdgcn_s_barrier();                                              \
    asm volatile("s_waitcnt lgkmcnt(0)" ::: "memory");                         \
    __builtin_amdgcn_sched_barrier(0);                                         \
    __builtin_amdgcn_s_setprio(1);                                             \
    _Pragma("unroll") for (int a = 0; a < AF; ++a)                             \
        _Pragma("unroll") for (int b = 0; b < BF; ++b)                         \
            acc[(mq) * AF + a][b] = mfma16(af[a], bf[b], acc[(mq) * AF + a][b]); \
    __builtin_amdgcn_s_setprio(0);                                             \
    __builtin_amdgcn_s_barrier();                                              \
  } while (0)

  // prologue: tiles 0,1 staged (except A(1,ks1), staged at ph1 of iter 0)
  STA(0, 0); STB(0, 0); STA(0, 1); STB(0, 1);
  STA(1, 0); STB(1, 0); STB(1, 1);
  VMW();  // tile-0 halves resident; 3 tile-1 halves in flight
  __builtin_amdgcn_s_barrier();

  for (int i = 0; i < (nk >> 1); ++i) {
    const int t1 = 2 * i + 1, t2 = 2 * i + 2, t3 = 2 * i + 3;
    LDA8(0, 0, 0); LDB8(0, 0); STA(t1, 1);          BARMM(0);  // ph1
    LDA8(0, 0, 1);             STB(t2, 0);          BARMM(1);  // ph2
    LDA8(0, 1, 0); LDB8(0, 1); STA(t2, 0);          BARMM(0);  // ph3
    LDA8(0, 1, 1);             STB(t2, 1); VMW();   BARMM(1);  // ph4
    LDA8(1, 0, 0); LDB8(1, 0); STA(t2, 1);          BARMM(0);  // ph5
    LDA8(1, 0, 1);             STB(t3, 0);          BARMM(1);  // ph6
    LDA8(1, 1, 0); LDB8(1, 1); STA(t3, 0);          BARMM(0);  // ph7
    LDA8(1, 1, 1);             STB(t3, 1); VMW();   BARMM(1);  // ph8
  }
  asm volatile("s_waitcnt vmcnt(0)" ::: "memory");

#pragma unroll
  for (int m = 0; m < MFR; ++m) {
#pragma unroll
    for (int n = 0; n < BF; ++n) {
      long mrow = m0 + wr * (BM / 2) + m * 16 + l4 * 4;
      long ncol = n0 + wc * (BN / 4) + n * 16 + l15;
#pragma unroll
      for (int r = 0; r < 4; ++r) {
        if constexpr (BF16OUT)
          ((ushort*)Cout)[(mrow + r) * N + ncol] = f2b(acc[m][n][r]);
        else
          ((float*)Cout)[(mrow + r) * N + ncol] = acc[m][n][r];
      }
    }
  }
#undef STA
#undef STB
#undef LDA8
#undef LDB8
#undef VMW
#undef BARMM
}

// ---------------- RMSnorm + RoPE + layout (q,k) / cast+transpose (v) --------
// V is written PERMUTED within each 32-key group so attn's PV A-fragments are
// contiguous: key k -> pos ((k>>2)&3)*8 + ((k>>4)&1)*4 + (k&3).
__global__ __launch_bounds__(256) void postproc_k(const ushort* __restrict__ qkvb,
                                                  const float* __restrict__ cosT,
                                                  const float* __restrict__ sinT,
                                                  ushort* __restrict__ qb,
                                                  ushort* __restrict__ kb,
                                                  ushort* __restrict__ vtb) {
  const int lane = threadIdx.x & 63;
  const int s = blockIdx.x * 4 + (threadIdx.x >> 6);
  const int h = blockIdx.y;
  const int colbase = (h < 16) ? h * 128 : (h < 20 ? 2048 + (h - 16) * 128
                                                   : 2560 + (h - 20) * 128);
  const ushort* row = qkvb + (long)s * 3072 + colbase;
  float x1 = b2f(row[lane]), x2 = b2f(row[lane + 64]);
  if (h >= 20) {  // V: cast + transpose to [kvh][128][S-permuted]
    int kvh = h - 20;
    int spos = (s & ~31) | (((s >> 2) & 3) * 8 + ((s >> 4) & 1) * 4 + (s & 3));
    vtb[(long)(kvh * 128 + lane) * 4096 + spos]      = f2b(x1);
    vtb[(long)(kvh * 128 + lane + 64) * 4096 + spos] = f2b(x2);
    return;
  }
  float ss = x1 * x1 + x2 * x2;
#pragma unroll
  for (int m = 1; m < 64; m <<= 1) ss += __shfl_xor(ss, m);
  float rn = rsqrtf(ss * (1.0f / 128.0f) + 1.1920929e-07f);
  float c = cosT[s * 64 + lane], sn = sinT[s * 64 + lane];
  float x1n = x1 * rn, x2n = x2 * rn;
  float o1 = x1n * c + x2n * sn;
  float o2 = x2n * c - x1n * sn;
  if (h < 16) {
    const float scq = 0.08838834764831845f;  // 1/sqrt(128) folded into q
    ushort* dst = qb + ((long)h * 4096 + s) * 128;
    dst[lane] = f2b(o1 * scq);
    dst[lane + 64] = f2b(o2 * scq);
  } else {
    ushort* dst = kb + ((long)(h - 16) * 4096 + s) * 128;
    dst[lane] = f2b(o1);
    dst[lane + 64] = f2b(o2);
  }
}

// ---------------- flash attention: LDS-staged K/V (fragment-major) ----------
// K LDS: 16 frags (16 rows x 32 cols), us = f*512 + (l4*16+l15)*8 -> QK^T
// reads are contiguous 1KB. V LDS: 16 frags (16 d-rows x 32 perm'd keys),
// us = f*512 + l15*32 + l4*8 -> each PV A-operand is one contiguous b128.
__global__ __launch_bounds__(512) void attn_k(const ushort* __restrict__ qb,
                                              const ushort* __restrict__ kb,
                                              const ushort* __restrict__ vtb,
                                              ushort* __restrict__ yb) {
  __shared__ __align__(16) ushort lds[32768];  // buf{0,1} x (K 8192us | V 8192us)
  const int t = threadIdx.x;
  const int lane = t & 63, w = t >> 6;
  const int l15 = lane & 15, l4 = lane >> 4;
  const int q0 = ((int)gridDim.x - 1 - (int)blockIdx.x) * 128;  // heavy first
  const int h = blockIdx.y, kvh = h >> 2;
  const int qw = q0 + w * 16;
  const int q = qw + l15;

  const ushort* Qp = qb + ((long)h * 4096 + q) * 128 + l4 * 8;
  bf16x8 qf[4];
#pragma unroll
  for (int c = 0; c < 4; ++c) qf[c] = *(const bf16x8*)(Qp + c * 32);

  const ushort* Kg = kb + (long)kvh * 4096 * 128;
  const ushort* Vg = vtb + (long)kvh * 128 * 4096;

  int kb_lo = q0 - 1023; if (kb_lo < 0) kb_lo = 0; kb_lo &= ~63;
  const int nt = (q0 + 127 - kb_lo) / 64 + 1;

  const int lbuA = w * 512 + lane * 8;       // 0..4095
  const int lbuB = lbuA + 4096;
  // K source coords (frag-major inverse map)
  const int krA = ((lbuA >> 9) >> 2) * 16 + ((lbuA >> 3) & 15);
  const int kcA = ((lbuA >> 9) & 3) * 32 + ((lbuA >> 7) & 3) * 8;
  const int krB = ((lbuB >> 9) >> 2) * 16 + ((lbuB >> 3) & 15);
  const int kcB = ((lbuB >> 9) & 3) * 32 + ((lbuB >> 7) & 3) * 8;
  // V source coords
  const int vrA = ((lbuA >> 9) >> 1) * 16 + ((lbuA >> 5) & 15);
  const int vcA = ((lbuA >> 9) & 1) * 32 + ((lbuA >> 3) & 3) * 8;
  const int vrB = ((lbuB >> 9) >> 1) * 16 + ((lbuB >> 5) & 15);
  const int vcB = ((lbuB >> 9) & 1) * 32 + ((lbuB >> 3) & 3) * 8;

#define STAGE(kbs, b)                                                        \
  do {                                                                       \
    ushort* Kl_ = &lds[(b) * 16384];                                         \
    ushort* Vl_ = &lds[(b) * 16384 + 8192];                                  \
    GLD_LDS16(Kg + (long)((kbs) + krA) * 128 + kcA, Kl_ + lbuA);             \
    GLD_LDS16(Kg + (long)((kbs) + krB) * 128 + kcB, Kl_ + lbuB);             \
    GLD_LDS16(Vg + (long)vrA * 4096 + (kbs) + vcA, Vl_ + lbuA);              \
    GLD_LDS16(Vg + (long)vrB * 4096 + (kbs) + vcB, Vl_ + lbuB);              \
  } while (0)

  f32x4 o[8] = {};
  float mrun = -1e30f, lrun = 0.0f;

  STAGE(kb_lo, 0);
  asm volatile("s_waitcnt vmcnt(0)" ::: "memory");
  __syncthreads();

  for (int ti = 0; ti < nt; ++ti) {
    const int kbs = kb_lo + ti * 64;
    const int cur = ti & 1;
    if (ti + 1 < nt) STAGE(kbs + 64, cur ^ 1);

    if (kbs + 63 >= qw - 1023 && kbs <= qw + 15) {
      const ushort* Kl = &lds[cur * 16384];
      const ushort* Vl = &lds[cur * 16384 + 8192];
      const int rdl = (l4 * 16 + l15) * 8;

      f32x4 sc[4];
#pragma unroll
      for (int st = 0; st < 4; ++st) {
        sc[st] = f32x4{0.f, 0.f, 0.f, 0.f};
#pragma unroll
        for (int c = 0; c < 4; ++c)
          sc[st] = mfma16(*(const bf16x8*)(Kl + (st * 4 + c) * 512 + rdl),
                          qf[c], sc[st]);
      }

      // wave-uniform fast path: interior tiles need no mask
      const bool full = (kbs + 64 <= qw) && (kbs >= qw - 1008);
      float s[16];
      if (full) {
#pragma unroll
        for (int st = 0; st < 4; ++st)
#pragma unroll
          for (int r = 0; r < 4; ++r) s[st * 4 + r] = sc[st][r];
      } else {
#pragma unroll
        for (int st = 0; st < 4; ++st)
#pragma unroll
          for (int r = 0; r < 4; ++r) {
            const int ki = kbs + st * 16 + l4 * 4 + r;
            s[st * 4 + r] = (ki <= q && ki > q - 1024) ? sc[st][r] : -1e30f;
          }
      }

      float m0a = fmaxf(fmaxf(s[0], s[1]), fmaxf(s[2], s[3]));
      float m1a = fmaxf(fmaxf(s[4], s[5]), fmaxf(s[6], s[7]));
      float m2a = fmaxf(fmaxf(s[8], s[9]), fmaxf(s[10], s[11]));
      float m3a = fmaxf(fmaxf(s[12], s[13]), fmaxf(s[14], s[15]));
      float mx = fmaxf(fmaxf(m0a, m1a), fmaxf(m2a, m3a));
      mx = fmaxf(mx, __shfl_xor(mx, 16));
      mx = fmaxf(mx, __shfl_xor(mx, 32));

      float mn;
      if (__all(mx <= mrun + 8.0f)) {  // T13 defer-max
        mn = mrun;
      } else {
        mn = fmaxf(mrun, mx);
        const float corr = __expf(mrun - mn);
        mrun = mn;
#pragma unroll
        for (int db = 0; db < 8; ++db)
#pragma unroll
          for (int r = 0; r < 4; ++r) o[db][r] *= corr;
        lrun *= corr;
      }

      float p[16];
#pragma unroll
      for (int j = 0; j < 16; ++j) p[j] = __expf(s[j] - mn);
      float ps = ((p[0] + p[1]) + (p[2] + p[3])) + ((p[4] + p[5]) + (p[6] + p[7]));
      ps += ((p[8] + p[9]) + (p[10] + p[11])) + ((p[12] + p[13]) + (p[14] + p[15]));
      ps += __shfl_xor(ps, 16);
      ps += __shfl_xor(ps, 32);
      lrun += ps;

      union { unsigned u[4]; bf16x8 v; } pa, pb;
      pa.u[0] = cvtpk(p[0], p[1]);   pa.u[1] = cvtpk(p[2], p[3]);
      pa.u[2] = cvtpk(p[4], p[5]);   pa.u[3] = cvtpk(p[6], p[7]);
      pb.u[0] = cvtpk(p[8], p[9]);   pb.u[1] = cvtpk(p[10], p[11]);
      pb.u[2] = cvtpk(p[12], p[13]); pb.u[3] = cvtpk(p[14], p[15]);

      const int vbase = l15 * 32 + l4 * 8;
#pragma unroll
      for (int db = 0; db < 8; ++db) {
        const ushort* vrp = Vl + db * 1024 + vbase;
        o[db] = mfma16(*(const bf16x8*)vrp, pa.v, o[db]);
        o[db] = mfma16(*(const bf16x8*)(vrp + 512), pb.v, o[db]);
      }
    }
    __syncthreads();
  }

  const float inv = 1.0f / lrun;
#pragma unroll
  for (int db = 0; db < 8; ++db)
#pragma unroll
    for (int r = 0; r < 4; ++r)
      yb[(long)q * 2048 + h * 128 + db * 16 + l4 * 4 + r] = f2b(o[db][r] * inv);
}

extern "C" void kernel_launch(void* const* d_in, const int* in_sizes, int n_in,
                              void* d_out, int out_size, void* d_ws, size_t ws_size,
                              hipStream_t stream) {
  (void)in_sizes; (void)n_in; (void)out_size; (void)ws_size;
  const float* x  = (const float*)d_in[0];
  const float* Wq = (const float*)d_in[1];
  const float* Wk = (const float*)d_in[2];
  const float* Wv = (const float*)d_in[3];
  const float* Wo = (const float*)d_in[4];
  const long S = 4096;
  ushort* ws   = (ushort*)d_ws;
  ushort* xb   = ws;                        // 4096*2048
  ushort* wqkv = xb + S * 2048;             // 3072*2048
  ushort* wob  = wqkv + 3072L * 2048;       // 2048*2048
  ushort* qkvb = wob + 2048L * 2048;        // 4096*3072
  ushort* qb   = qkvb + S * 3072;           // 16*4096*128
  ushort* kbuf = qb + S * 2048;             // 4*4096*128
  ushort* vtb  = kbuf + 4L * 4096 * 128;    // 4*128*4096 (key-permuted)
  ushort* yb   = vtb + 4L * 128 * 4096;     // 4096*2048
  float* cosT  = (float*)(yb + S * 2048);   // 4096*64
  float* sinT  = cosT + S * 64;             // 4096*64

  cast_bf16<<<dim3(8192), 256, 0, stream>>>(x, xb, (int)(S * 2048 / 4));
  cast_bf16<<<dim3(4096), 256, 0, stream>>>(Wq, wqkv, 2048 * 2048 / 4);
  cast_bf16<<<dim3(1024), 256, 0, stream>>>(Wk, wqkv + 2048L * 2048, 512 * 2048 / 4);
  cast_bf16<<<dim3(1024), 256, 0, stream>>>(Wv, wqkv + 2560L * 2048, 512 * 2048 / 4);
  cast_bf16<<<dim3(4096), 256, 0, stream>>>(Wo, wob, 2048 * 2048 / 4);

  gemm8p<256, 256, true><<<dim3(192), 512, 0, stream>>>(xb, wqkv, qkvb, 4096, 3072, 2048);
  rope_tables_k<<<dim3(4096), 64, 0, stream>>>(cosT, sinT);
  postproc_k<<<dim3(1024, 24), 256, 0, stream>>>(qkvb, cosT, sinT, qb, kbuf, vtb);
  attn_k<<<dim3(32, 16), 512, 0, stream>>>(qb, kbuf, vtb, yb);
  gemm8p<128, 256, false><<<dim3(256), 512, 0, stream>>>(yb, wob, d_out, 4096, 2048, 2048);
}